// Round 1
// baseline (65.664 us; speedup 1.0000x reference)
//
#include <hip/hip_runtime.h>

typedef __attribute__((ext_vector_type(4))) float f32x4;

#define D_ 64
#define K_ 512
#define QB 128
#define KB 128
#define NCHUNK (K_ / KB)
#define MT 8
#define NT 8
#define NTHREADS 256

__device__ __forceinline__ void gload_lds16(const float* g, float* lds) {
  __builtin_amdgcn_global_load_lds(
      (const __attribute__((address_space(1))) void*)g,
      (__attribute__((address_space(3))) void*)lds, 16, 0, 0);
}

__global__ __launch_bounds__(NTHREADS, 2)
void vq_assign_gather(const float* __restrict__ codes,
                      const float* __restrict__ codebook,
                      float* __restrict__ out) {
  __shared__ float A[QB * D_];      // codes tile  [q][d], 32 KB
  __shared__ float Bt[D_ * KB];     // codebook chunk transposed [d][e], 32 KB
  __shared__ float esq_s[KB];       // squared norms of chunk entries
  __shared__ int best_s[QB];        // final argmin per query

  const int t = threadIdx.x;
  const int tx = t & 15;            // entry-group (16 groups x 8 entries)
  const int ty = t >> 4;            // query-group (16 groups x 8 queries)
  const long long qbase = (long long)blockIdx.x * QB;

  // ---- stage codes tile (32 KB) via async global->LDS, 16 B/lane ----
  {
    const float* src = codes + qbase * D_;
    const int wv = (t >> 6) & 3;    // wave id (uniform per wave)
#pragma unroll
    for (int r = 0; r < 8; ++r)
      gload_lds16(src + r * 1024 + t * 4, A + r * 1024 + wv * 256);
  }

  // ---- codebook chunk staging (reg-staged, transposed into LDS) ----
  const int se = t >> 1;            // entry 0..127 within chunk
  const int sdh = (t & 1) * 32;     // d-half 0 or 32
  f32x4 pre[8];

  auto load_chunk = [&](int c) {
    const float* g = codebook + (c * KB + se) * D_ + sdh;
#pragma unroll
    for (int i = 0; i < 8; ++i) pre[i] = *(const f32x4*)(g + 4 * i);
  };
  auto write_chunk = [&]() {
    float ps = 0.f;
#pragma unroll
    for (int i = 0; i < 8; ++i) {
#pragma unroll
      for (int j = 0; j < 4; ++j) {
        float v = pre[i][j];
        Bt[(sdh + 4 * i + j) * KB + se] = v;   // transpose: [d][e]
        ps += v * v;
      }
    }
    ps += __shfl_xor(ps, 1, 64);               // combine the two d-halves
    if ((t & 1) == 0) esq_s[se] = ps;
  };

  float minv[MT];
  int mini[MT];
#pragma unroll
  for (int m = 0; m < MT; ++m) { minv[m] = 3.4e38f; mini[m] = 0; }

  load_chunk(0);
  write_chunk();
  __syncthreads();                  // drains A-stage vmcnt too

  for (int c = 0; c < NCHUNK; ++c) {
    if (c + 1 < NCHUNK) load_chunk(c + 1);   // issue-early (T14)

    float acc[MT][NT];
#pragma unroll
    for (int m = 0; m < MT; ++m)
#pragma unroll
      for (int n = 0; n < NT; ++n) acc[m][n] = 0.f;

    const float* Arow = A + (ty * MT) * D_;
    const float* Brow = Bt + tx * NT;

#pragma unroll 2
    for (int d0 = 0; d0 < D_; d0 += 4) {
      f32x4 a[MT];
#pragma unroll
      for (int m = 0; m < MT; ++m) a[m] = *(const f32x4*)(Arow + m * D_ + d0);
      f32x4 b0[4], b1[4];
#pragma unroll
      for (int dd = 0; dd < 4; ++dd) {
        b0[dd] = *(const f32x4*)(Brow + (d0 + dd) * KB);
        b1[dd] = *(const f32x4*)(Brow + (d0 + dd) * KB + 4);
      }
#pragma unroll
      for (int dd = 0; dd < 4; ++dd) {
#pragma unroll
        for (int m = 0; m < MT; ++m) {
#pragma unroll
          for (int n = 0; n < 4; ++n) acc[m][n] += a[m][dd] * b0[dd][n];
#pragma unroll
          for (int n = 0; n < 4; ++n) acc[m][4 + n] += a[m][dd] * b1[dd][n];
        }
      }
    }

    // score = 0.5*||e||^2 - c.e  (same ordering as ||c-e||^2, c_sq dropped)
    const int ebase = c * KB + tx * NT;
#pragma unroll
    for (int n = 0; n < NT; ++n) {
      float sc_base = 0.5f * esq_s[tx * NT + n];
#pragma unroll
      for (int m = 0; m < MT; ++m) {
        float sc = sc_base - acc[m][n];
        if (sc < minv[m]) { minv[m] = sc; mini[m] = ebase + n; }  // strict <: first-min wins
      }
    }

    __syncthreads();                // everyone done reading Bt
    if (c + 1 < NCHUNK) {
      write_chunk();                // write-late (vmcnt drained by use)
      __syncthreads();
    }
  }

  // ---- cross-lane argmin across the 16 tx-lanes sharing each query ----
#pragma unroll
  for (int off = 1; off < 16; off <<= 1) {
#pragma unroll
    for (int m = 0; m < MT; ++m) {
      float ov = __shfl_xor(minv[m], off, 64);
      int oi = __shfl_xor(mini[m], off, 64);
      if (ov < minv[m] || (ov == minv[m] && oi < mini[m])) {
        minv[m] = ov; mini[m] = oi;
      }
    }
  }
  if (tx == 0) {
#pragma unroll
    for (int m = 0; m < MT; ++m) best_s[ty * MT + m] = mini[m];
  }
  __syncthreads();

  // ---- gather: out[q][:] = codebook[best[q]][:]  (coalesced float4) ----
#pragma unroll
  for (int i = 0; i < 8; ++i) {
    int f = t + NTHREADS * i;       // float4 index, 2048 per block
    int q = f >> 4;                 // 16 float4 per row
    int c4 = f & 15;
    int e = best_s[q];
    f32x4 v = *(const f32x4*)(codebook + e * D_ + c4 * 4);
    *(f32x4*)(out + (qbase + q) * D_ + c4 * 4) = v;
  }
}

extern "C" void kernel_launch(void* const* d_in, const int* in_sizes, int n_in,
                              void* d_out, int out_size, void* d_ws, size_t ws_size,
                              hipStream_t stream) {
  const float* codes = (const float*)d_in[0];
  const float* codebook = (const float*)d_in[1];
  float* out = (float*)d_out;
  const int Q = in_sizes[0] / D_;   // 65536
  const int grid = Q / QB;          // 512
  vq_assign_gather<<<grid, NTHREADS, 0, stream>>>(codes, codebook, out);
}